// Round 12
// baseline (389.068 us; speedup 1.0000x reference)
//
#include <hip/hip_runtime.h>
#include <hip/hip_bf16.h>

#define D 128
#define EPS 1e-8f
#define E1S 136
#define PS  136

typedef _Float16 f16;
typedef __attribute__((ext_vector_type(8))) _Float16 half8;
typedef __attribute__((ext_vector_type(4))) float f32x4;
typedef unsigned int uint;

__device__ inline float2 up2(uint u) {      // unpack 2 packed fp16 -> floats
    union { uint u; f16 h[2]; } v; v.u = u;
    return make_float2((float)v.h[0], (float)v.h[1]);
}

// ---------------- K0 (merged prologue): normalize | hist | prep ----------------
__global__ void k_prologue(const float* __restrict__ H, f16* __restrict__ HT,
                           const int* __restrict__ src, int* __restrict__ deg,
                           const float* __restrict__ w1_1, const float* __restrict__ w1_2,
                           const float* __restrict__ w2_1, f16* __restrict__ Wt,
                           int N, int E, int nbN) {
    int b = blockIdx.x;
    int t = threadIdx.x;
    if (b < nbN) {
        int row = b * 4 + (t >> 6);
        int lane = t & 63;
        if (row >= N) return;
        float2 v = reinterpret_cast<const float2*>(H + (size_t)row * D)[lane];
        float ss = v.x * v.x + v.y * v.y;
        #pragma unroll
        for (int off = 32; off; off >>= 1) ss += __shfl_xor(ss, off, 64);
        float scale = 1.0f / (sqrtf(ss) + EPS);
        union { f16 h[2]; uint u; } p;
        p.h[0] = (f16)(v.x * scale);
        p.h[1] = (f16)(v.y * scale);
        reinterpret_cast<uint*>(HT + (size_t)row * 256)[lane] = p.u;
    } else if (b < nbN + 1024) {
        int bb = b - nbN;
        for (int e = bb * 256 + t; e < E; e += 1024 * 256)
            atomicAdd(&deg[src[e]], 1);
    } else {
        int bb = b - nbN - 1024;                  // 0..319
        int m = bb >> 6;
        int idx = (bb & 63) * 256 + t;
        int k = idx >> 7, n = idx & 127;
        const float* W = (m == 0) ? w1_1
                       : (m == 1) ? w1_1 + 16384
                       : (m == 2) ? w1_2
                       : (m == 3) ? w2_1
                                  : w2_1 + 16384;
        Wt[m * 16384 + n * 128 + k] = (f16)W[k * 128 + n];
    }
}

// ---------------- CSR scan + scatter ----------------
__global__ void k_scan(const int* __restrict__ deg, int* __restrict__ rowptr, int N) {
    __shared__ int wsum[16];
    __shared__ int carry;
    int t = threadIdx.x, lane = t & 63, w = t >> 6;
    if (t == 0) carry = 0;
    __syncthreads();
    for (int base = 0; base < N; base += 4096) {
        int i0 = base + t * 4;
        int a = 0, b = 0, c = 0, d = 0;
        if (i0 + 3 < N) {
            int4 v4 = *reinterpret_cast<const int4*>(deg + i0);
            a = v4.x; b = v4.y; c = v4.z; d = v4.w;
        } else {
            if (i0 < N) a = deg[i0];
            if (i0 + 1 < N) b = deg[i0 + 1];
            if (i0 + 2 < N) c = deg[i0 + 2];
            if (i0 + 3 < N) d = deg[i0 + 3];
        }
        int s1 = a + b, s2 = s1 + c, s3 = s2 + d;
        int v = s3;
        #pragma unroll
        for (int off = 1; off < 64; off <<= 1) {
            int u = __shfl_up(v, off, 64);
            if (lane >= off) v += u;
        }
        if (lane == 63) wsum[w] = v;
        __syncthreads();
        if (w == 0 && lane < 16) {
            int s = wsum[lane];
            #pragma unroll
            for (int off = 1; off < 16; off <<= 1) {
                int u = __shfl_up(s, off, 64);
                if (lane >= off) s += u;
            }
            wsum[lane] = s;
        }
        __syncthreads();
        int add = (w > 0 ? wsum[w - 1] : 0) + carry;
        int incl = v + add;
        int pre = incl - s3;
        if (i0 < N)     rowptr[i0 + 1] = pre + a;
        if (i0 + 1 < N) rowptr[i0 + 2] = pre + s1;
        if (i0 + 2 < N) rowptr[i0 + 3] = pre + s2;
        if (i0 + 3 < N) rowptr[i0 + 4] = pre + s3;
        __syncthreads();
        if (t == 1023) carry = incl;
        __syncthreads();
    }
    if (t == 0) rowptr[0] = 0;
}

__global__ void k_scatter(const int* __restrict__ src, const int* __restrict__ dst,
                          const int* __restrict__ rowptr, int* __restrict__ fill,
                          int* __restrict__ srcS, int* __restrict__ dstS, int E) {
    for (int e = blockIdx.x * blockDim.x + threadIdx.x; e < E; e += gridDim.x * blockDim.x) {
        int s = src[e];
        int pos = atomicAdd(&fill[s], 1);
        int idx = rowptr[s] + pos;
        srcS[idx] = s;
        dstS[idx] = dst[e];
    }
}

// ---------------- dual MFMA GEMM: A[N x 128] @ {Wt0,Wt1} -> fp16 out0(+bias0), out1 ----------------
template <bool A_F16>
__global__ __launch_bounds__(256, 4)
void k_gemm_dual(const void* __restrict__ Aptr, const f16* __restrict__ Wt0,
                 const f16* __restrict__ Wt1, const float* __restrict__ bias0,
                 f16* __restrict__ out0, f16* __restrict__ out1, int N,
                 int astr, int o1str) {
    __shared__ f16 As[64 * E1S];
    int t = threadIdx.x;
    int r0 = blockIdx.x * 64;
    int l = t & 63, w = t >> 6, n0 = w * 32;
    {
        int er = t >> 2, kb = (t & 3) * 32;
        int rc = min(r0 + er, N - 1);
        if (A_F16) {
            const half8* Ap = reinterpret_cast<const half8*>((const f16*)Aptr + (size_t)rc * astr + kb);
            #pragma unroll
            for (int q = 0; q < 4; ++q)
                *reinterpret_cast<half8*>(&As[er * E1S + kb + q * 8]) = Ap[q];
        } else {
            const float4* Ap = reinterpret_cast<const float4*>((const float*)Aptr + (size_t)rc * astr + kb);
            #pragma unroll
            for (int q = 0; q < 4; ++q) {
                float4 a0 = Ap[q * 2], a1 = Ap[q * 2 + 1];
                half8 sv;
                sv[0] = (f16)a0.x; sv[1] = (f16)a0.y; sv[2] = (f16)a0.z; sv[3] = (f16)a0.w;
                sv[4] = (f16)a1.x; sv[5] = (f16)a1.y; sv[6] = (f16)a1.z; sv[7] = (f16)a1.w;
                *reinterpret_cast<half8*>(&As[er * E1S + kb + q * 8]) = sv;
            }
        }
    }
    half8 bfrag[2][4];
    #pragma unroll
    for (int nt = 0; nt < 2; ++nt) {
        int col = n0 + nt * 16 + (l & 15);
        #pragma unroll
        for (int kt = 0; kt < 4; ++kt)
            bfrag[nt][kt] = *reinterpret_cast<const half8*>(Wt0 + col * 128 + kt * 32 + (l >> 4) * 8);
    }
    float b0a = bias0[n0 + (l & 15)];
    float b0b = bias0[n0 + 16 + (l & 15)];
    __syncthreads();
    f32x4 acc0[4][2], acc1[4][2];
    #pragma unroll
    for (int mt = 0; mt < 4; ++mt) {
        acc0[mt][0] = (f32x4){0,0,0,0}; acc0[mt][1] = (f32x4){0,0,0,0};
        acc1[mt][0] = (f32x4){0,0,0,0}; acc1[mt][1] = (f32x4){0,0,0,0};
    }
    #pragma unroll
    for (int mt = 0; mt < 4; ++mt) {
        int arow = mt * 16 + (l & 15);
        #pragma unroll
        for (int kt = 0; kt < 4; ++kt) {
            half8 af = *reinterpret_cast<const half8*>(&As[arow * E1S + kt * 32 + (l >> 4) * 8]);
            acc0[mt][0] = __builtin_amdgcn_mfma_f32_16x16x32_f16(af, bfrag[0][kt], acc0[mt][0], 0, 0, 0);
            acc0[mt][1] = __builtin_amdgcn_mfma_f32_16x16x32_f16(af, bfrag[1][kt], acc0[mt][1], 0, 0, 0);
        }
    }
    #pragma unroll
    for (int nt = 0; nt < 2; ++nt) {
        int col = n0 + nt * 16 + (l & 15);
        #pragma unroll
        for (int kt = 0; kt < 4; ++kt)
            bfrag[nt][kt] = *reinterpret_cast<const half8*>(Wt1 + col * 128 + kt * 32 + (l >> 4) * 8);
    }
    #pragma unroll
    for (int mt = 0; mt < 4; ++mt) {
        int arow = mt * 16 + (l & 15);
        #pragma unroll
        for (int kt = 0; kt < 4; ++kt) {
            half8 af = *reinterpret_cast<const half8*>(&As[arow * E1S + kt * 32 + (l >> 4) * 8]);
            acc1[mt][0] = __builtin_amdgcn_mfma_f32_16x16x32_f16(af, bfrag[0][kt], acc1[mt][0], 0, 0, 0);
            acc1[mt][1] = __builtin_amdgcn_mfma_f32_16x16x32_f16(af, bfrag[1][kt], acc1[mt][1], 0, 0, 0);
        }
    }
    __syncthreads();
    #pragma unroll
    for (int mt = 0; mt < 4; ++mt)
        #pragma unroll
        for (int j = 0; j < 4; ++j) {
            int row = mt * 16 + (l >> 4) * 4 + j;
            As[row * E1S + n0 + (l & 15)]      = (f16)(acc0[mt][0][j] + b0a);
            As[row * E1S + n0 + 16 + (l & 15)] = (f16)(acc0[mt][1][j] + b0b);
        }
    __syncthreads();
    {
        int er = t >> 2, kb = (t & 3) * 32;
        int row = r0 + er;
        if (row < N)
            #pragma unroll
            for (int q = 0; q < 4; ++q)
                *reinterpret_cast<half8*>(out0 + (size_t)row * 128 + kb + q * 8) =
                    *reinterpret_cast<const half8*>(&As[er * E1S + kb + q * 8]);
    }
    __syncthreads();
    #pragma unroll
    for (int mt = 0; mt < 4; ++mt)
        #pragma unroll
        for (int j = 0; j < 4; ++j) {
            int row = mt * 16 + (l >> 4) * 4 + j;
            As[row * E1S + n0 + (l & 15)]      = (f16)acc1[mt][0][j];
            As[row * E1S + n0 + 16 + (l & 15)] = (f16)acc1[mt][1][j];
        }
    __syncthreads();
    {
        int er = t >> 2, kb = (t & 3) * 32;
        int row = r0 + er;
        if (row < N)
            #pragma unroll
            for (int q = 0; q < 4; ++q)
                *reinterpret_cast<half8*>(out1 + (size_t)row * o1str + kb + q * 8) =
                    *reinterpret_cast<const half8*>(&As[er * E1S + kb + q * 8]);
    }
}

// ---------------- K3 (hot): persistent mlp1 — B amortized, P-dedup via LDS ----------------
__global__ __launch_bounds__(256, 5)
void k_edge_mlp1(const int* __restrict__ srcS, const int* __restrict__ dstS,
                 const int* __restrict__ rowptr,
                 const f16* __restrict__ P, const f16* __restrict__ Q,
                 const f16* __restrict__ Wt, const float* __restrict__ b1_2,
                 float* __restrict__ C, int E, int ntiles) {
    __shared__ f16 e1s[64 * E1S];        // 17408 B
    __shared__ f16 Pstage[32 * PS];      // 8704 B
    __shared__ int ssrc_l[64], sdst_l[64], pslot_l[64], hsrc_l[64];
    __shared__ int nh_l;
    int t = threadIdx.x;
    int l = t & 63, w = t >> 6, n0 = w * 32;
    int er = t >> 2, kb = (t & 3) * 32;

    // persistent: B fragments + bias loaded once per block
    half8 bfrag[2][4];
    #pragma unroll
    for (int nt = 0; nt < 2; ++nt) {
        int col = n0 + nt * 16 + (l & 15);
        #pragma unroll
        for (int kt = 0; kt < 4; ++kt)
            bfrag[nt][kt] = *reinterpret_cast<const half8*>(Wt + col * 128 + kt * 32 + (l >> 4) * 8);
    }
    float bias0 = b1_2[n0 + (l & 15)];
    float bias1 = b1_2[n0 + 16 + (l & 15)];

    for (int tile = blockIdx.x; tile < ntiles; tile += gridDim.x) {
        int e0 = tile * 64;
        __syncthreads();                 // protect LDS from previous tile's readers
        if (t < 64) {                    // wave 0: indices + head scan
            int ge = min(e0 + t, E - 1);
            int s0 = srcS[ge];
            ssrc_l[t] = s0;
            sdst_l[t] = dstS[ge];
            int sp = __shfl_up(s0, 1, 64);
            int head = (t == 0 || s0 != sp) ? 1 : 0;
            int incl = head;
            #pragma unroll
            for (int off = 1; off < 64; off <<= 1) {
                int u = __shfl_up(incl, off, 64);
                if (t >= off) incl += u;
            }
            pslot_l[t] = incl - 1;
            if (head) hsrc_l[incl - 1] = s0;
            if (t == 63) nh_l = incl;
        }
        __syncthreads();
        int nh = nh_l;
        if (nh <= 32) {                  // stage distinct P rows into LDS
            for (int i = t; i < nh * 16; i += 256) {
                int slot = i >> 4, ch = i & 15;
                *reinterpret_cast<half8*>(&Pstage[slot * PS + ch * 8]) =
                    *reinterpret_cast<const half8*>(P + (size_t)hsrc_l[slot] * 128 + ch * 8);
            }
        }
        __syncthreads();
        // e1 stage: relu(P'[src] + Q[dst]) -> e1s
        {
            int dj = sdst_l[er];
            const half8* Qp = reinterpret_cast<const half8*>(Q + (size_t)dj * 128 + kb);
            half8 p[4];
            if (nh <= 32) {
                const half8* Pp = reinterpret_cast<const half8*>(&Pstage[pslot_l[er] * PS + kb]);
                #pragma unroll
                for (int q = 0; q < 4; ++q) p[q] = Pp[q];
            } else {
                const half8* Pp = reinterpret_cast<const half8*>(P + (size_t)ssrc_l[er] * 128 + kb);
                #pragma unroll
                for (int q = 0; q < 4; ++q) p[q] = Pp[q];
            }
            #pragma unroll
            for (int q = 0; q < 4; ++q) {
                half8 sv = p[q] + Qp[q];
                #pragma unroll
                for (int i = 0; i < 8; ++i)
                    sv[i] = sv[i] > (f16)0 ? sv[i] : (f16)0;
                *reinterpret_cast<half8*>(&e1s[er * E1S + kb + q * 8]) = sv;
            }
        }
        __syncthreads();
        // MFMA
        f32x4 acc[4][2];
        #pragma unroll
        for (int mt = 0; mt < 4; ++mt) { acc[mt][0] = (f32x4){0,0,0,0}; acc[mt][1] = (f32x4){0,0,0,0}; }
        #pragma unroll
        for (int mt = 0; mt < 4; ++mt) {
            int arow = mt * 16 + (l & 15);
            #pragma unroll
            for (int kt = 0; kt < 4; ++kt) {
                half8 af = *reinterpret_cast<const half8*>(&e1s[arow * E1S + kt * 32 + (l >> 4) * 8]);
                acc[mt][0] = __builtin_amdgcn_mfma_f32_16x16x32_f16(af, bfrag[0][kt], acc[mt][0], 0, 0, 0);
                acc[mt][1] = __builtin_amdgcn_mfma_f32_16x16x32_f16(af, bfrag[1][kt], acc[mt][1], 0, 0, 0);
            }
        }
        #pragma unroll
        for (int mt = 0; mt < 4; ++mt)
            #pragma unroll
            for (int j = 0; j < 4; ++j) {
                acc[mt][0][j] = fmaxf(acc[mt][0][j] + bias0, 0.f);
                acc[mt][1][j] = fmaxf(acc[mt][1][j] + bias1, 0.f);
            }
        // in-register segmented reduce over MFMA rows (= edges), mt-tile skipped
        int myv = (e0 + l < E) ? ssrc_l[l] : -1;
        int pv = __shfl_up(myv, 1, 64);
        bool head = (l == 0) || (myv != pv);
        unsigned long long validm = __ballot(myv >= 0);
        unsigned long long hm = __ballot(head) & validm;
        int nvalid = __popcll(validm);
        int grp = l >> 4;
        while (hm) {
            int lo = __builtin_ctzll(hm);
            hm &= hm - 1;
            int hi = hm ? __builtin_ctzll(hm) : nvalid;
            int s = __shfl(myv, lo, 64);
            float v0 = 0.f, v1 = 0.f;
            #pragma unroll
            for (int mt = 0; mt < 4; ++mt) {
                int tlo = mt * 16, thi = mt * 16 + 16;
                if (thi <= lo || tlo >= hi) continue;          // wave-uniform skip
                if (lo <= tlo && hi >= thi) {                  // full tile: plain adds
                    #pragma unroll
                    for (int j = 0; j < 4; ++j) {
                        v0 += acc[mt][0][j];
                        v1 += acc[mt][1][j];
                    }
                } else {                                       // partial tile: masked adds
                    #pragma unroll
                    for (int j = 0; j < 4; ++j) {
                        int row = tlo + grp * 4 + j;
                        bool in = (row >= lo) && (row < hi);
                        v0 += in ? acc[mt][0][j] : 0.f;
                        v1 += in ? acc[mt][1][j] : 0.f;
                    }
                }
            }
            v0 += __shfl_xor(v0, 16, 64); v0 += __shfl_xor(v0, 32, 64);
            v1 += __shfl_xor(v1, 16, 64); v1 += __shfl_xor(v1, 32, 64);
            if (l < 16) {
                int rs = rowptr[s], re = rowptr[s + 1];
                float* cp = C + (size_t)s * 128 + n0 + l;
                if (rs >= e0 && re <= e0 + 64) {
                    cp[0] = v0; cp[16] = v1;
                } else {
                    atomicAdd(cp, v0); atomicAdd(cp + 16, v1);
                }
            }
        }
    }
}

// ---------------- K5: fused node curvature, 4-slot + prefetch, HT-interleaved gathers ----------------
__global__ void k_node_curv(const int* __restrict__ dstS, const int* __restrict__ rowptr,
                            const f16* __restrict__ HT, const f16* __restrict__ Rb,
                            const float* __restrict__ w2_2, const float* __restrict__ b2_2,
                            float* __restrict__ out, int N) {
    int node = blockIdx.x * 4 + (threadIdx.x >> 6);
    int lane = threadIdx.x & 63;
    if (node >= N) return;
    int sub = lane & 15;
    int slot = lane >> 4;
    const uint4* HTU = reinterpret_cast<const uint4*>(HT);
    uint4 hiu = HTU[(size_t)node * 32 + sub];
    uint4 rvu = reinterpret_cast<const uint4*>(Rb)[(size_t)node * 16 + sub];
    float hif[8], rvf[8], wvf[8];
    {
        const uint* hp = &hiu.x;
        const uint* rp = &rvu.x;
        float4 w0 = reinterpret_cast<const float4*>(w2_2)[sub * 2];
        float4 w1 = reinterpret_cast<const float4*>(w2_2)[sub * 2 + 1];
        #pragma unroll
        for (int k = 0; k < 4; ++k) {
            float2 h = up2(hp[k]); hif[k * 2] = h.x; hif[k * 2 + 1] = h.y;
            float2 r = up2(rp[k]); rvf[k * 2] = r.x; rvf[k * 2 + 1] = r.y;
        }
        wvf[0] = w0.x; wvf[1] = w0.y; wvf[2] = w0.z; wvf[3] = w0.w;
        wvf[4] = w1.x; wvf[5] = w1.y; wvf[6] = w1.z; wvf[7] = w1.w;
    }
    float bb = b2_2[0];
    int lo = rowptr[node], hiE = rowptr[node + 1];
    int deg = hiE - lo;
    float ax[8];
    #pragma unroll
    for (int j = 0; j < 8; ++j) ax[j] = 0.f;
    float sc = 0.f;
    int e = lo + slot;
    bool valid = e < hiE;
    int dcur = valid ? dstS[e] : 0;
    uint4 hju = HTU[(size_t)dcur * 32 + sub];
    uint4 tvu = HTU[(size_t)dcur * 32 + 16 + sub];
    for (int it = 0; it < deg; it += 4) {
        int e2 = lo + it + 4 + slot;
        bool valid2 = e2 < hiE;
        int d2 = valid2 ? dstS[e2] : 0;
        uint4 hjN = HTU[(size_t)d2 * 32 + sub];
        uint4 tvN = HTU[(size_t)d2 * 32 + 16 + sub];
        float hjf[8];
        float pcos = 0.f, pcur = 0.f;
        {
            const uint* hp = &hju.x;
            const uint* tp = &tvu.x;
            #pragma unroll
            for (int k = 0; k < 4; ++k) {
                float2 h = up2(hp[k]);
                float2 tv = up2(tp[k]);
                hjf[k * 2] = h.x; hjf[k * 2 + 1] = h.y;
                pcos += hif[k * 2] * h.x + hif[k * 2 + 1] * h.y;
                pcur += fmaxf(rvf[k * 2] + tv.x, 0.f) * wvf[k * 2]
                      + fmaxf(rvf[k * 2 + 1] + tv.y, 0.f) * wvf[k * 2 + 1];
            }
        }
        #pragma unroll
        for (int off = 1; off < 16; off <<= 1) {
            pcos += __shfl_xor(pcos, off, 64);
            pcur += __shfl_xor(pcur, off, 64);
        }
        float cur = valid ? (pcur + bb) : 0.f;
        #pragma unroll
        for (int j = 0; j < 8; ++j) ax[j] += cur * hjf[j];
        sc += cur * pcos;
        hju = hjN; tvu = tvN; valid = valid2;
    }
    #pragma unroll
    for (int j = 0; j < 8; ++j) {
        ax[j] += __shfl_xor(ax[j], 16, 64);
        ax[j] += __shfl_xor(ax[j], 32, 64);
    }
    sc += __shfl_xor(sc, 16, 64);
    sc += __shfl_xor(sc, 32, 64);
    float inv = 1.0f / fmaxf((float)deg, 1.0f);
    float ss = 0.f;
    #pragma unroll
    for (int j = 0; j < 8; ++j) {
        ax[j] = (ax[j] - sc * hif[j]) * inv;
        ss += ax[j] * ax[j];
    }
    #pragma unroll
    for (int off = 1; off < 16; off <<= 1) ss += __shfl_xor(ss, off, 64);
    float scale = 1.0f / (sqrtf(ss) + EPS);
    if (slot == 0) {
        float4 o0 = make_float4(ax[0] * scale, ax[1] * scale, ax[2] * scale, ax[3] * scale);
        float4 o1 = make_float4(ax[4] * scale, ax[5] * scale, ax[6] * scale, ax[7] * scale);
        float4* op = reinterpret_cast<float4*>(out + (size_t)node * 128 + sub * 8);
        op[0] = o0;
        op[1] = o1;
    }
}

extern "C" void kernel_launch(void* const* d_in, const int* in_sizes, int n_in,
                              void* d_out, int out_size, void* d_ws, size_t ws_size,
                              hipStream_t stream) {
    const float* H    = (const float*)d_in[1];
    const int*   ei   = (const int*)d_in[2];
    const float* w1_1 = (const float*)d_in[3];
    const float* b1_1 = (const float*)d_in[4];
    const float* w1_2 = (const float*)d_in[5];
    const float* b1_2 = (const float*)d_in[6];
    const float* w2_1 = (const float*)d_in[7];
    const float* b2_1 = (const float*)d_in[8];
    const float* w2_2 = (const float*)d_in[9];
    const float* b2_2 = (const float*)d_in[10];

    int N = in_sizes[1] / D;
    int E = in_sizes[2] / 2;
    const int* src = ei;
    const int* dst = ei + E;

    float* out = (float*)d_out;

    // Workspace layout
    f16* HT     = (f16*)d_ws;                     // N*256 fp16: [Hn | T]
    f16* Pb     = HT + (size_t)N * 256;           // N*128 fp16 (P', later R')
    f16* Qb     = Pb + (size_t)N * D;             // N*128 fp16 (Q)
    float* Cb   = (float*)(Qb + (size_t)N * D);   // N*128 fp32
    f16* Wt     = (f16*)(Cb + (size_t)N * D);     // 5 * 128*128 fp16
    int* deg    = (int*)(Wt + 5 * 16384);         // N
    int* rowptr = deg + N;                        // N+1
    int* fill   = rowptr + N + 1;                 // N
    int* srcS   = fill + N;                       // E
    int* dstS   = srcS + E;                       // E

    hipMemsetAsync(Cb, 0, (size_t)N * D * sizeof(float), stream);
    hipMemsetAsync(deg, 0, (3 * (size_t)N + 1) * sizeof(int), stream);

    int nbN = (N + 3) / 4;
    k_prologue<<<nbN + 1024 + 320, 256, 0, stream>>>(H, HT, src, deg,
                                                     w1_1, w1_2, w2_1, Wt, N, E, nbN);
    k_scan<<<1, 1024, 0, stream>>>(deg, rowptr, N);
    k_scatter<<<1024, 256, 0, stream>>>(src, dst, rowptr, fill, srcS, dstS, E);

    int ntiles = (E + 63) / 64;
    k_gemm_dual<true><<<(N + 63) / 64, 256, 0, stream>>>(HT, Wt + 0 * 16384, Wt + 1 * 16384,
                                                         b1_1, Pb, Qb, N, 256, 128);
    k_edge_mlp1<<<1280, 256, 0, stream>>>(srcS, dstS, rowptr, Pb, Qb,
                                          Wt + 2 * 16384, b1_2, Cb, E, ntiles);
    k_gemm_dual<false><<<(N + 63) / 64, 256, 0, stream>>>(Cb, Wt + 3 * 16384, Wt + 4 * 16384,
                                                          b2_1, Pb, HT + 128, N, 128, 256);
    k_node_curv<<<(N + 3) / 4, 256, 0, stream>>>(dstS, rowptr, HT, Pb, w2_2, b2_2, out, N);
}

// Round 13
// 340.164 us; speedup vs baseline: 1.1438x; 1.1438x over previous
//
#include <hip/hip_runtime.h>
#include <hip/hip_bf16.h>

#define D 128
#define EPS 1e-8f
#define E1S 136

typedef _Float16 f16;
typedef __attribute__((ext_vector_type(8))) _Float16 half8;
typedef __attribute__((ext_vector_type(4))) float f32x4;
typedef unsigned int uint;

__device__ inline float2 up2(uint u) {      // unpack 2 packed fp16 -> floats
    union { uint u; f16 h[2]; } v; v.u = u;
    return make_float2((float)v.h[0], (float)v.h[1]);
}

// ---------------- K0 (merged prologue): normalize | hist | prep ----------------
__global__ void k_prologue(const float* __restrict__ H, f16* __restrict__ HT,
                           const int* __restrict__ src, int* __restrict__ deg,
                           const float* __restrict__ w1_1, const float* __restrict__ w1_2,
                           const float* __restrict__ w2_1, f16* __restrict__ Wt,
                           int N, int E, int nbN) {
    int b = blockIdx.x;
    int t = threadIdx.x;
    if (b < nbN) {
        int row = b * 4 + (t >> 6);
        int lane = t & 63;
        if (row >= N) return;
        float2 v = reinterpret_cast<const float2*>(H + (size_t)row * D)[lane];
        float ss = v.x * v.x + v.y * v.y;
        #pragma unroll
        for (int off = 32; off; off >>= 1) ss += __shfl_xor(ss, off, 64);
        float scale = 1.0f / (sqrtf(ss) + EPS);
        union { f16 h[2]; uint u; } p;
        p.h[0] = (f16)(v.x * scale);
        p.h[1] = (f16)(v.y * scale);
        reinterpret_cast<uint*>(HT + (size_t)row * 256)[lane] = p.u;
    } else if (b < nbN + 1024) {
        int bb = b - nbN;
        for (int e = bb * 256 + t; e < E; e += 1024 * 256)
            atomicAdd(&deg[src[e]], 1);
    } else {
        int bb = b - nbN - 1024;                  // 0..319
        int m = bb >> 6;
        int idx = (bb & 63) * 256 + t;
        int k = idx >> 7, n = idx & 127;
        const float* W = (m == 0) ? w1_1
                       : (m == 1) ? w1_1 + 16384
                       : (m == 2) ? w1_2
                       : (m == 3) ? w2_1
                                  : w2_1 + 16384;
        Wt[m * 16384 + n * 128 + k] = (f16)W[k * 128 + n];
    }
}

// ---------------- CSR scan + scatter ----------------
__global__ void k_scan(const int* __restrict__ deg, int* __restrict__ rowptr, int N) {
    __shared__ int wsum[16];
    __shared__ int carry;
    int t = threadIdx.x, lane = t & 63, w = t >> 6;
    if (t == 0) carry = 0;
    __syncthreads();
    for (int base = 0; base < N; base += 4096) {
        int i0 = base + t * 4;
        int a = 0, b = 0, c = 0, d = 0;
        if (i0 + 3 < N) {
            int4 v4 = *reinterpret_cast<const int4*>(deg + i0);
            a = v4.x; b = v4.y; c = v4.z; d = v4.w;
        } else {
            if (i0 < N) a = deg[i0];
            if (i0 + 1 < N) b = deg[i0 + 1];
            if (i0 + 2 < N) c = deg[i0 + 2];
            if (i0 + 3 < N) d = deg[i0 + 3];
        }
        int s1 = a + b, s2 = s1 + c, s3 = s2 + d;
        int v = s3;
        #pragma unroll
        for (int off = 1; off < 64; off <<= 1) {
            int u = __shfl_up(v, off, 64);
            if (lane >= off) v += u;
        }
        if (lane == 63) wsum[w] = v;
        __syncthreads();
        if (w == 0 && lane < 16) {
            int s = wsum[lane];
            #pragma unroll
            for (int off = 1; off < 16; off <<= 1) {
                int u = __shfl_up(s, off, 64);
                if (lane >= off) s += u;
            }
            wsum[lane] = s;
        }
        __syncthreads();
        int add = (w > 0 ? wsum[w - 1] : 0) + carry;
        int incl = v + add;
        int pre = incl - s3;
        if (i0 < N)     rowptr[i0 + 1] = pre + a;
        if (i0 + 1 < N) rowptr[i0 + 2] = pre + s1;
        if (i0 + 2 < N) rowptr[i0 + 3] = pre + s2;
        if (i0 + 3 < N) rowptr[i0 + 4] = pre + s3;
        __syncthreads();
        if (t == 1023) carry = incl;
        __syncthreads();
    }
    if (t == 0) rowptr[0] = 0;
}

__global__ void k_scatter(const int* __restrict__ src, const int* __restrict__ dst,
                          const int* __restrict__ rowptr, int* __restrict__ fill,
                          int* __restrict__ srcS, int* __restrict__ dstS, int E) {
    for (int e = blockIdx.x * blockDim.x + threadIdx.x; e < E; e += gridDim.x * blockDim.x) {
        int s = src[e];
        int pos = atomicAdd(&fill[s], 1);
        int idx = rowptr[s] + pos;
        srcS[idx] = s;
        dstS[idx] = dst[e];
    }
}

// ---------------- dual MFMA GEMM: A[N x 128] @ {Wt0,Wt1} -> fp16 out0(+bias0), out1 ----------------
template <bool A_F16>
__global__ __launch_bounds__(256, 4)
void k_gemm_dual(const void* __restrict__ Aptr, const f16* __restrict__ Wt0,
                 const f16* __restrict__ Wt1, const float* __restrict__ bias0,
                 f16* __restrict__ out0, f16* __restrict__ out1, int N,
                 int astr, int o1str) {
    __shared__ f16 As[64 * E1S];
    int t = threadIdx.x;
    int r0 = blockIdx.x * 64;
    int l = t & 63, w = t >> 6, n0 = w * 32;
    {
        int er = t >> 2, kb = (t & 3) * 32;
        int rc = min(r0 + er, N - 1);
        if (A_F16) {
            const half8* Ap = reinterpret_cast<const half8*>((const f16*)Aptr + (size_t)rc * astr + kb);
            #pragma unroll
            for (int q = 0; q < 4; ++q)
                *reinterpret_cast<half8*>(&As[er * E1S + kb + q * 8]) = Ap[q];
        } else {
            const float4* Ap = reinterpret_cast<const float4*>((const float*)Aptr + (size_t)rc * astr + kb);
            #pragma unroll
            for (int q = 0; q < 4; ++q) {
                float4 a0 = Ap[q * 2], a1 = Ap[q * 2 + 1];
                half8 sv;
                sv[0] = (f16)a0.x; sv[1] = (f16)a0.y; sv[2] = (f16)a0.z; sv[3] = (f16)a0.w;
                sv[4] = (f16)a1.x; sv[5] = (f16)a1.y; sv[6] = (f16)a1.z; sv[7] = (f16)a1.w;
                *reinterpret_cast<half8*>(&As[er * E1S + kb + q * 8]) = sv;
            }
        }
    }
    half8 bfrag[2][4];
    #pragma unroll
    for (int nt = 0; nt < 2; ++nt) {
        int col = n0 + nt * 16 + (l & 15);
        #pragma unroll
        for (int kt = 0; kt < 4; ++kt)
            bfrag[nt][kt] = *reinterpret_cast<const half8*>(Wt0 + col * 128 + kt * 32 + (l >> 4) * 8);
    }
    float b0a = bias0[n0 + (l & 15)];
    float b0b = bias0[n0 + 16 + (l & 15)];
    __syncthreads();
    f32x4 acc0[4][2], acc1[4][2];
    #pragma unroll
    for (int mt = 0; mt < 4; ++mt) {
        acc0[mt][0] = (f32x4){0,0,0,0}; acc0[mt][1] = (f32x4){0,0,0,0};
        acc1[mt][0] = (f32x4){0,0,0,0}; acc1[mt][1] = (f32x4){0,0,0,0};
    }
    #pragma unroll
    for (int mt = 0; mt < 4; ++mt) {
        int arow = mt * 16 + (l & 15);
        #pragma unroll
        for (int kt = 0; kt < 4; ++kt) {
            half8 af = *reinterpret_cast<const half8*>(&As[arow * E1S + kt * 32 + (l >> 4) * 8]);
            acc0[mt][0] = __builtin_amdgcn_mfma_f32_16x16x32_f16(af, bfrag[0][kt], acc0[mt][0], 0, 0, 0);
            acc0[mt][1] = __builtin_amdgcn_mfma_f32_16x16x32_f16(af, bfrag[1][kt], acc0[mt][1], 0, 0, 0);
        }
    }
    #pragma unroll
    for (int nt = 0; nt < 2; ++nt) {
        int col = n0 + nt * 16 + (l & 15);
        #pragma unroll
        for (int kt = 0; kt < 4; ++kt)
            bfrag[nt][kt] = *reinterpret_cast<const half8*>(Wt1 + col * 128 + kt * 32 + (l >> 4) * 8);
    }
    #pragma unroll
    for (int mt = 0; mt < 4; ++mt) {
        int arow = mt * 16 + (l & 15);
        #pragma unroll
        for (int kt = 0; kt < 4; ++kt) {
            half8 af = *reinterpret_cast<const half8*>(&As[arow * E1S + kt * 32 + (l >> 4) * 8]);
            acc1[mt][0] = __builtin_amdgcn_mfma_f32_16x16x32_f16(af, bfrag[0][kt], acc1[mt][0], 0, 0, 0);
            acc1[mt][1] = __builtin_amdgcn_mfma_f32_16x16x32_f16(af, bfrag[1][kt], acc1[mt][1], 0, 0, 0);
        }
    }
    __syncthreads();
    #pragma unroll
    for (int mt = 0; mt < 4; ++mt)
        #pragma unroll
        for (int j = 0; j < 4; ++j) {
            int row = mt * 16 + (l >> 4) * 4 + j;
            As[row * E1S + n0 + (l & 15)]      = (f16)(acc0[mt][0][j] + b0a);
            As[row * E1S + n0 + 16 + (l & 15)] = (f16)(acc0[mt][1][j] + b0b);
        }
    __syncthreads();
    {
        int er = t >> 2, kb = (t & 3) * 32;
        int row = r0 + er;
        if (row < N)
            #pragma unroll
            for (int q = 0; q < 4; ++q)
                *reinterpret_cast<half8*>(out0 + (size_t)row * 128 + kb + q * 8) =
                    *reinterpret_cast<const half8*>(&As[er * E1S + kb + q * 8]);
    }
    __syncthreads();
    #pragma unroll
    for (int mt = 0; mt < 4; ++mt)
        #pragma unroll
        for (int j = 0; j < 4; ++j) {
            int row = mt * 16 + (l >> 4) * 4 + j;
            As[row * E1S + n0 + (l & 15)]      = (f16)acc1[mt][0][j];
            As[row * E1S + n0 + 16 + (l & 15)] = (f16)acc1[mt][1][j];
        }
    __syncthreads();
    {
        int er = t >> 2, kb = (t & 3) * 32;
        int row = r0 + er;
        if (row < N)
            #pragma unroll
            for (int q = 0; q < 4; ++q)
                *reinterpret_cast<half8*>(out1 + (size_t)row * o1str + kb + q * 8) =
                    *reinterpret_cast<const half8*>(&As[er * E1S + kb + q * 8]);
    }
}

// ---------------- K3 (hot): per-edge mlp1 layer2 (R11 structure) + bijective XCD tile swizzle ----------------
__global__ __launch_bounds__(256, 5)
void k_edge_mlp1(const int* __restrict__ srcS, const int* __restrict__ dstS,
                 const int* __restrict__ rowptr,
                 const f16* __restrict__ P, const f16* __restrict__ Q,
                 const f16* __restrict__ Wt, const float* __restrict__ b1_2,
                 float* __restrict__ C, int E) {
    __shared__ f16 e1s[64 * E1S];
    int t = threadIdx.x;
    // bijective XCD-chunked swizzle (m204): XCD x's resident blocks walk a
    // CONTIGUOUS tile chunk -> P gathers stay in a narrow src window (L2-resident).
    int nwg = gridDim.x;
    int orig = blockIdx.x;
    int xcd = orig & 7;
    int loc = orig >> 3;
    int qq = nwg >> 3, rr = nwg & 7;
    int tile = (xcd < rr ? xcd * (qq + 1) : rr * (qq + 1) + (xcd - rr) * qq) + loc;
    int e0 = tile * 64;
    int l = t & 63, w = t >> 6, n0 = w * 32;
    // stage e1 = relu(P'[src] + Q[dst])   (b1_1 folded into P'), pure packed fp16
    {
        int er = t >> 2, kb = (t & 3) * 32;
        int ge = min(e0 + er, E - 1);
        int sc = srcS[ge], dj = dstS[ge];
        const half8* Pp = reinterpret_cast<const half8*>(P + (size_t)sc * 128 + kb);
        const half8* Qp = reinterpret_cast<const half8*>(Q + (size_t)dj * 128 + kb);
        #pragma unroll
        for (int q = 0; q < 4; ++q) {
            half8 sv = Pp[q] + Qp[q];
            #pragma unroll
            for (int i = 0; i < 8; ++i)
                sv[i] = sv[i] > (f16)0 ? sv[i] : (f16)0;
            *reinterpret_cast<half8*>(&e1s[er * E1S + kb + q * 8]) = sv;
        }
    }
    half8 bfrag[2][4];
    #pragma unroll
    for (int nt = 0; nt < 2; ++nt) {
        int col = n0 + nt * 16 + (l & 15);
        #pragma unroll
        for (int kt = 0; kt < 4; ++kt)
            bfrag[nt][kt] = *reinterpret_cast<const half8*>(Wt + col * 128 + kt * 32 + (l >> 4) * 8);
    }
    float bias0 = b1_2[n0 + (l & 15)];
    float bias1 = b1_2[n0 + 16 + (l & 15)];
    __syncthreads();
    f32x4 acc[4][2];
    #pragma unroll
    for (int mt = 0; mt < 4; ++mt) { acc[mt][0] = (f32x4){0,0,0,0}; acc[mt][1] = (f32x4){0,0,0,0}; }
    #pragma unroll
    for (int mt = 0; mt < 4; ++mt) {
        int arow = mt * 16 + (l & 15);
        #pragma unroll
        for (int kt = 0; kt < 4; ++kt) {
            half8 af = *reinterpret_cast<const half8*>(&e1s[arow * E1S + kt * 32 + (l >> 4) * 8]);
            acc[mt][0] = __builtin_amdgcn_mfma_f32_16x16x32_f16(af, bfrag[0][kt], acc[mt][0], 0, 0, 0);
            acc[mt][1] = __builtin_amdgcn_mfma_f32_16x16x32_f16(af, bfrag[1][kt], acc[mt][1], 0, 0, 0);
        }
    }
    #pragma unroll
    for (int mt = 0; mt < 4; ++mt)
        #pragma unroll
        for (int j = 0; j < 4; ++j) {
            acc[mt][0][j] = fmaxf(acc[mt][0][j] + bias0, 0.f);
            acc[mt][1][j] = fmaxf(acc[mt][1][j] + bias1, 0.f);
        }
    // in-register segmented reduce over MFMA rows (= edges), mt-tile skipped
    int myv = (e0 + l < E) ? srcS[e0 + l] : -1;
    int pv = __shfl_up(myv, 1, 64);
    bool head = (l == 0) || (myv != pv);
    unsigned long long validm = __ballot(myv >= 0);
    unsigned long long hm = __ballot(head) & validm;
    int nvalid = __popcll(validm);
    int grp = l >> 4;
    while (hm) {
        int lo = __builtin_ctzll(hm);
        hm &= hm - 1;
        int hi = hm ? __builtin_ctzll(hm) : nvalid;
        int s = __shfl(myv, lo, 64);
        float v0 = 0.f, v1 = 0.f;
        #pragma unroll
        for (int mt = 0; mt < 4; ++mt) {
            int tlo = mt * 16, thi = mt * 16 + 16;
            if (thi <= lo || tlo >= hi) continue;          // wave-uniform skip
            if (lo <= tlo && hi >= thi) {                  // full tile: plain adds
                #pragma unroll
                for (int j = 0; j < 4; ++j) {
                    v0 += acc[mt][0][j];
                    v1 += acc[mt][1][j];
                }
            } else {                                       // partial tile: masked adds
                #pragma unroll
                for (int j = 0; j < 4; ++j) {
                    int row = tlo + grp * 4 + j;
                    bool in = (row >= lo) && (row < hi);
                    v0 += in ? acc[mt][0][j] : 0.f;
                    v1 += in ? acc[mt][1][j] : 0.f;
                }
            }
        }
        v0 += __shfl_xor(v0, 16, 64); v0 += __shfl_xor(v0, 32, 64);
        v1 += __shfl_xor(v1, 16, 64); v1 += __shfl_xor(v1, 32, 64);
        if (l < 16) {
            int rs = rowptr[s], re = rowptr[s + 1];
            float* cp = C + (size_t)s * 128 + n0 + l;
            if (rs >= e0 && re <= e0 + 64) {
                cp[0] = v0; cp[16] = v1;
            } else {
                atomicAdd(cp, v0); atomicAdd(cp + 16, v1);
            }
        }
    }
}

// ---------------- K5: fused node curvature, 4-slot + prefetch, HT-interleaved gathers ----------------
__global__ void k_node_curv(const int* __restrict__ dstS, const int* __restrict__ rowptr,
                            const f16* __restrict__ HT, const f16* __restrict__ Rb,
                            const float* __restrict__ w2_2, const float* __restrict__ b2_2,
                            float* __restrict__ out, int N) {
    int node = blockIdx.x * 4 + (threadIdx.x >> 6);
    int lane = threadIdx.x & 63;
    if (node >= N) return;
    int sub = lane & 15;
    int slot = lane >> 4;
    const uint4* HTU = reinterpret_cast<const uint4*>(HT);
    uint4 hiu = HTU[(size_t)node * 32 + sub];
    uint4 rvu = reinterpret_cast<const uint4*>(Rb)[(size_t)node * 16 + sub];
    float hif[8], rvf[8], wvf[8];
    {
        const uint* hp = &hiu.x;
        const uint* rp = &rvu.x;
        float4 w0 = reinterpret_cast<const float4*>(w2_2)[sub * 2];
        float4 w1 = reinterpret_cast<const float4*>(w2_2)[sub * 2 + 1];
        #pragma unroll
        for (int k = 0; k < 4; ++k) {
            float2 h = up2(hp[k]); hif[k * 2] = h.x; hif[k * 2 + 1] = h.y;
            float2 r = up2(rp[k]); rvf[k * 2] = r.x; rvf[k * 2 + 1] = r.y;
        }
        wvf[0] = w0.x; wvf[1] = w0.y; wvf[2] = w0.z; wvf[3] = w0.w;
        wvf[4] = w1.x; wvf[5] = w1.y; wvf[6] = w1.z; wvf[7] = w1.w;
    }
    float bb = b2_2[0];
    int lo = rowptr[node], hiE = rowptr[node + 1];
    int deg = hiE - lo;
    float ax[8];
    #pragma unroll
    for (int j = 0; j < 8; ++j) ax[j] = 0.f;
    float sc = 0.f;
    int e = lo + slot;
    bool valid = e < hiE;
    int dcur = valid ? dstS[e] : 0;
    uint4 hju = HTU[(size_t)dcur * 32 + sub];
    uint4 tvu = HTU[(size_t)dcur * 32 + 16 + sub];
    for (int it = 0; it < deg; it += 4) {
        int e2 = lo + it + 4 + slot;
        bool valid2 = e2 < hiE;
        int d2 = valid2 ? dstS[e2] : 0;
        uint4 hjN = HTU[(size_t)d2 * 32 + sub];
        uint4 tvN = HTU[(size_t)d2 * 32 + 16 + sub];
        float hjf[8];
        float pcos = 0.f, pcur = 0.f;
        {
            const uint* hp = &hju.x;
            const uint* tp = &tvu.x;
            #pragma unroll
            for (int k = 0; k < 4; ++k) {
                float2 h = up2(hp[k]);
                float2 tv = up2(tp[k]);
                hjf[k * 2] = h.x; hjf[k * 2 + 1] = h.y;
                pcos += hif[k * 2] * h.x + hif[k * 2 + 1] * h.y;
                pcur += fmaxf(rvf[k * 2] + tv.x, 0.f) * wvf[k * 2]
                      + fmaxf(rvf[k * 2 + 1] + tv.y, 0.f) * wvf[k * 2 + 1];
            }
        }
        #pragma unroll
        for (int off = 1; off < 16; off <<= 1) {
            pcos += __shfl_xor(pcos, off, 64);
            pcur += __shfl_xor(pcur, off, 64);
        }
        float cur = valid ? (pcur + bb) : 0.f;
        #pragma unroll
        for (int j = 0; j < 8; ++j) ax[j] += cur * hjf[j];
        sc += cur * pcos;
        hju = hjN; tvu = tvN; valid = valid2;
    }
    #pragma unroll
    for (int j = 0; j < 8; ++j) {
        ax[j] += __shfl_xor(ax[j], 16, 64);
        ax[j] += __shfl_xor(ax[j], 32, 64);
    }
    sc += __shfl_xor(sc, 16, 64);
    sc += __shfl_xor(sc, 32, 64);
    float inv = 1.0f / fmaxf((float)deg, 1.0f);
    float ss = 0.f;
    #pragma unroll
    for (int j = 0; j < 8; ++j) {
        ax[j] = (ax[j] - sc * hif[j]) * inv;
        ss += ax[j] * ax[j];
    }
    #pragma unroll
    for (int off = 1; off < 16; off <<= 1) ss += __shfl_xor(ss, off, 64);
    float scale = 1.0f / (sqrtf(ss) + EPS);
    if (slot == 0) {
        float4 o0 = make_float4(ax[0] * scale, ax[1] * scale, ax[2] * scale, ax[3] * scale);
        float4 o1 = make_float4(ax[4] * scale, ax[5] * scale, ax[6] * scale, ax[7] * scale);
        float4* op = reinterpret_cast<float4*>(out + (size_t)node * 128 + sub * 8);
        op[0] = o0;
        op[1] = o1;
    }
}

extern "C" void kernel_launch(void* const* d_in, const int* in_sizes, int n_in,
                              void* d_out, int out_size, void* d_ws, size_t ws_size,
                              hipStream_t stream) {
    const float* H    = (const float*)d_in[1];
    const int*   ei   = (const int*)d_in[2];
    const float* w1_1 = (const float*)d_in[3];
    const float* b1_1 = (const float*)d_in[4];
    const float* w1_2 = (const float*)d_in[5];
    const float* b1_2 = (const float*)d_in[6];
    const float* w2_1 = (const float*)d_in[7];
    const float* b2_1 = (const float*)d_in[8];
    const float* w2_2 = (const float*)d_in[9];
    const float* b2_2 = (const float*)d_in[10];

    int N = in_sizes[1] / D;
    int E = in_sizes[2] / 2;
    const int* src = ei;
    const int* dst = ei + E;

    float* out = (float*)d_out;

    // Workspace layout
    f16* HT     = (f16*)d_ws;                     // N*256 fp16: [Hn | T]
    f16* Pb     = HT + (size_t)N * 256;           // N*128 fp16 (P', later R')
    f16* Qb     = Pb + (size_t)N * D;             // N*128 fp16 (Q)
    float* Cb   = (float*)(Qb + (size_t)N * D);   // N*128 fp32
    f16* Wt     = (f16*)(Cb + (size_t)N * D);     // 5 * 128*128 fp16
    int* deg    = (int*)(Wt + 5 * 16384);         // N
    int* rowptr = deg + N;                        // N+1
    int* fill   = rowptr + N + 1;                 // N
    int* srcS   = fill + N;                       // E
    int* dstS   = srcS + E;                       // E

    hipMemsetAsync(Cb, 0, (size_t)N * D * sizeof(float), stream);
    hipMemsetAsync(deg, 0, (3 * (size_t)N + 1) * sizeof(int), stream);

    int nbN = (N + 3) / 4;
    k_prologue<<<nbN + 1024 + 320, 256, 0, stream>>>(H, HT, src, deg,
                                                     w1_1, w1_2, w2_1, Wt, N, E, nbN);
    k_scan<<<1, 1024, 0, stream>>>(deg, rowptr, N);
    k_scatter<<<1024, 256, 0, stream>>>(src, dst, rowptr, fill, srcS, dstS, E);

    k_gemm_dual<true><<<(N + 63) / 64, 256, 0, stream>>>(HT, Wt + 0 * 16384, Wt + 1 * 16384,
                                                         b1_1, Pb, Qb, N, 256, 128);
    k_edge_mlp1<<<(E + 63) / 64, 256, 0, stream>>>(srcS, dstS, rowptr, Pb, Qb,
                                                   Wt + 2 * 16384, b1_2, Cb, E);
    k_gemm_dual<false><<<(N + 63) / 64, 256, 0, stream>>>(Cb, Wt + 3 * 16384, Wt + 4 * 16384,
                                                          b2_1, Pb, HT + 128, N, 128, 256);
    k_node_curv<<<(N + 3) / 4, 256, 0, stream>>>(dstS, rowptr, HT, Pb, w2_2, b2_2, out, N);
}

// Round 14
// 337.436 us; speedup vs baseline: 1.1530x; 1.0081x over previous
//
#include <hip/hip_runtime.h>
#include <hip/hip_bf16.h>

#define D 128
#define EPS 1e-8f
#define E1S 136

typedef _Float16 f16;
typedef __attribute__((ext_vector_type(8))) _Float16 half8;
typedef __attribute__((ext_vector_type(4))) float f32x4;
typedef unsigned int uint;

__device__ inline float2 up2(uint u) {      // unpack 2 packed fp16 -> floats
    union { uint u; f16 h[2]; } v; v.u = u;
    return make_float2((float)v.h[0], (float)v.h[1]);
}

// ---------------- K0 (merged prologue): normalize | hist | prep ----------------
__global__ void k_prologue(const float* __restrict__ H, f16* __restrict__ HT,
                           const int* __restrict__ src, int* __restrict__ deg,
                           const float* __restrict__ w1_1, const float* __restrict__ w1_2,
                           const float* __restrict__ w2_1, f16* __restrict__ Wt,
                           int N, int E, int nbN) {
    int b = blockIdx.x;
    int t = threadIdx.x;
    if (b < nbN) {
        int row = b * 4 + (t >> 6);
        int lane = t & 63;
        if (row >= N) return;
        float2 v = reinterpret_cast<const float2*>(H + (size_t)row * D)[lane];
        float ss = v.x * v.x + v.y * v.y;
        #pragma unroll
        for (int off = 32; off; off >>= 1) ss += __shfl_xor(ss, off, 64);
        float scale = 1.0f / (sqrtf(ss) + EPS);
        union { f16 h[2]; uint u; } p;
        p.h[0] = (f16)(v.x * scale);
        p.h[1] = (f16)(v.y * scale);
        reinterpret_cast<uint*>(HT + (size_t)row * 256)[lane] = p.u;
    } else if (b < nbN + 1024) {
        int bb = b - nbN;
        for (int e = bb * 256 + t; e < E; e += 1024 * 256)
            atomicAdd(&deg[src[e]], 1);
    } else {
        int bb = b - nbN - 1024;                  // 0..319
        int m = bb >> 6;
        int idx = (bb & 63) * 256 + t;
        int k = idx >> 7, n = idx & 127;
        const float* W = (m == 0) ? w1_1
                       : (m == 1) ? w1_1 + 16384
                       : (m == 2) ? w1_2
                       : (m == 3) ? w2_1
                                  : w2_1 + 16384;
        Wt[m * 16384 + n * 128 + k] = (f16)W[k * 128 + n];
    }
}

// ---------------- CSR scan + scatter ----------------
__global__ void k_scan(const int* __restrict__ deg, int* __restrict__ rowptr, int N) {
    __shared__ int wsum[16];
    __shared__ int carry;
    int t = threadIdx.x, lane = t & 63, w = t >> 6;
    if (t == 0) carry = 0;
    __syncthreads();
    for (int base = 0; base < N; base += 4096) {
        int i0 = base + t * 4;
        int a = 0, b = 0, c = 0, d = 0;
        if (i0 + 3 < N) {
            int4 v4 = *reinterpret_cast<const int4*>(deg + i0);
            a = v4.x; b = v4.y; c = v4.z; d = v4.w;
        } else {
            if (i0 < N) a = deg[i0];
            if (i0 + 1 < N) b = deg[i0 + 1];
            if (i0 + 2 < N) c = deg[i0 + 2];
            if (i0 + 3 < N) d = deg[i0 + 3];
        }
        int s1 = a + b, s2 = s1 + c, s3 = s2 + d;
        int v = s3;
        #pragma unroll
        for (int off = 1; off < 64; off <<= 1) {
            int u = __shfl_up(v, off, 64);
            if (lane >= off) v += u;
        }
        if (lane == 63) wsum[w] = v;
        __syncthreads();
        if (w == 0 && lane < 16) {
            int s = wsum[lane];
            #pragma unroll
            for (int off = 1; off < 16; off <<= 1) {
                int u = __shfl_up(s, off, 64);
                if (lane >= off) s += u;
            }
            wsum[lane] = s;
        }
        __syncthreads();
        int add = (w > 0 ? wsum[w - 1] : 0) + carry;
        int incl = v + add;
        int pre = incl - s3;
        if (i0 < N)     rowptr[i0 + 1] = pre + a;
        if (i0 + 1 < N) rowptr[i0 + 2] = pre + s1;
        if (i0 + 2 < N) rowptr[i0 + 3] = pre + s2;
        if (i0 + 3 < N) rowptr[i0 + 4] = pre + s3;
        __syncthreads();
        if (t == 1023) carry = incl;
        __syncthreads();
    }
    if (t == 0) rowptr[0] = 0;
}

__global__ void k_scatter(const int* __restrict__ src, const int* __restrict__ dst,
                          const int* __restrict__ rowptr, int* __restrict__ fill,
                          int* __restrict__ srcS, int* __restrict__ dstS, int E) {
    for (int e = blockIdx.x * blockDim.x + threadIdx.x; e < E; e += gridDim.x * blockDim.x) {
        int s = src[e];
        int pos = atomicAdd(&fill[s], 1);
        int idx = rowptr[s] + pos;
        srcS[idx] = s;
        dstS[idx] = dst[e];
    }
}

// ---------------- dual MFMA GEMM: A[N x 128] @ {Wt0,Wt1} -> fp16 out0(+bias0), out1 ----------------
template <bool A_F16>
__global__ __launch_bounds__(256, 4)
void k_gemm_dual(const void* __restrict__ Aptr, const f16* __restrict__ Wt0,
                 const f16* __restrict__ Wt1, const float* __restrict__ bias0,
                 f16* __restrict__ out0, f16* __restrict__ out1, int N,
                 int astr, int o1str) {
    __shared__ f16 As[64 * E1S];
    int t = threadIdx.x;
    int r0 = blockIdx.x * 64;
    int l = t & 63, w = t >> 6, n0 = w * 32;
    {
        int er = t >> 2, kb = (t & 3) * 32;
        int rc = min(r0 + er, N - 1);
        if (A_F16) {
            const half8* Ap = reinterpret_cast<const half8*>((const f16*)Aptr + (size_t)rc * astr + kb);
            #pragma unroll
            for (int q = 0; q < 4; ++q)
                *reinterpret_cast<half8*>(&As[er * E1S + kb + q * 8]) = Ap[q];
        } else {
            const float4* Ap = reinterpret_cast<const float4*>((const float*)Aptr + (size_t)rc * astr + kb);
            #pragma unroll
            for (int q = 0; q < 4; ++q) {
                float4 a0 = Ap[q * 2], a1 = Ap[q * 2 + 1];
                half8 sv;
                sv[0] = (f16)a0.x; sv[1] = (f16)a0.y; sv[2] = (f16)a0.z; sv[3] = (f16)a0.w;
                sv[4] = (f16)a1.x; sv[5] = (f16)a1.y; sv[6] = (f16)a1.z; sv[7] = (f16)a1.w;
                *reinterpret_cast<half8*>(&As[er * E1S + kb + q * 8]) = sv;
            }
        }
    }
    half8 bfrag[2][4];
    #pragma unroll
    for (int nt = 0; nt < 2; ++nt) {
        int col = n0 + nt * 16 + (l & 15);
        #pragma unroll
        for (int kt = 0; kt < 4; ++kt)
            bfrag[nt][kt] = *reinterpret_cast<const half8*>(Wt0 + col * 128 + kt * 32 + (l >> 4) * 8);
    }
    float b0a = bias0[n0 + (l & 15)];
    float b0b = bias0[n0 + 16 + (l & 15)];
    __syncthreads();
    f32x4 acc0[4][2], acc1[4][2];
    #pragma unroll
    for (int mt = 0; mt < 4; ++mt) {
        acc0[mt][0] = (f32x4){0,0,0,0}; acc0[mt][1] = (f32x4){0,0,0,0};
        acc1[mt][0] = (f32x4){0,0,0,0}; acc1[mt][1] = (f32x4){0,0,0,0};
    }
    #pragma unroll
    for (int mt = 0; mt < 4; ++mt) {
        int arow = mt * 16 + (l & 15);
        #pragma unroll
        for (int kt = 0; kt < 4; ++kt) {
            half8 af = *reinterpret_cast<const half8*>(&As[arow * E1S + kt * 32 + (l >> 4) * 8]);
            acc0[mt][0] = __builtin_amdgcn_mfma_f32_16x16x32_f16(af, bfrag[0][kt], acc0[mt][0], 0, 0, 0);
            acc0[mt][1] = __builtin_amdgcn_mfma_f32_16x16x32_f16(af, bfrag[1][kt], acc0[mt][1], 0, 0, 0);
        }
    }
    #pragma unroll
    for (int nt = 0; nt < 2; ++nt) {
        int col = n0 + nt * 16 + (l & 15);
        #pragma unroll
        for (int kt = 0; kt < 4; ++kt)
            bfrag[nt][kt] = *reinterpret_cast<const half8*>(Wt1 + col * 128 + kt * 32 + (l >> 4) * 8);
    }
    #pragma unroll
    for (int mt = 0; mt < 4; ++mt) {
        int arow = mt * 16 + (l & 15);
        #pragma unroll
        for (int kt = 0; kt < 4; ++kt) {
            half8 af = *reinterpret_cast<const half8*>(&As[arow * E1S + kt * 32 + (l >> 4) * 8]);
            acc1[mt][0] = __builtin_amdgcn_mfma_f32_16x16x32_f16(af, bfrag[0][kt], acc1[mt][0], 0, 0, 0);
            acc1[mt][1] = __builtin_amdgcn_mfma_f32_16x16x32_f16(af, bfrag[1][kt], acc1[mt][1], 0, 0, 0);
        }
    }
    __syncthreads();
    #pragma unroll
    for (int mt = 0; mt < 4; ++mt)
        #pragma unroll
        for (int j = 0; j < 4; ++j) {
            int row = mt * 16 + (l >> 4) * 4 + j;
            As[row * E1S + n0 + (l & 15)]      = (f16)(acc0[mt][0][j] + b0a);
            As[row * E1S + n0 + 16 + (l & 15)] = (f16)(acc0[mt][1][j] + b0b);
        }
    __syncthreads();
    {
        int er = t >> 2, kb = (t & 3) * 32;
        int row = r0 + er;
        if (row < N)
            #pragma unroll
            for (int q = 0; q < 4; ++q)
                *reinterpret_cast<half8*>(out0 + (size_t)row * 128 + kb + q * 8) =
                    *reinterpret_cast<const half8*>(&As[er * E1S + kb + q * 8]);
    }
    __syncthreads();
    #pragma unroll
    for (int mt = 0; mt < 4; ++mt)
        #pragma unroll
        for (int j = 0; j < 4; ++j) {
            int row = mt * 16 + (l >> 4) * 4 + j;
            As[row * E1S + n0 + (l & 15)]      = (f16)acc1[mt][0][j];
            As[row * E1S + n0 + 16 + (l & 15)] = (f16)acc1[mt][1][j];
        }
    __syncthreads();
    {
        int er = t >> 2, kb = (t & 3) * 32;
        int row = r0 + er;
        if (row < N)
            #pragma unroll
            for (int q = 0; q < 4; ++q)
                *reinterpret_cast<half8*>(out1 + (size_t)row * o1str + kb + q * 8) =
                    *reinterpret_cast<const half8*>(&As[er * E1S + kb + q * 8]);
    }
}

// ---------------- K3 (hot): mlp1 layer2 — COALESCED row-gather staging (16 lanes/row) ----------------
__global__ __launch_bounds__(256, 5)
void k_edge_mlp1(const int* __restrict__ srcS, const int* __restrict__ dstS,
                 const int* __restrict__ rowptr,
                 const f16* __restrict__ P, const f16* __restrict__ Q,
                 const f16* __restrict__ Wt, const float* __restrict__ b1_2,
                 float* __restrict__ C, int E) {
    __shared__ f16 e1s[64 * E1S];
    int t = threadIdx.x;
    // bijective XCD-chunked swizzle (kept from R13; small FETCH win, no cost)
    int nwg = gridDim.x;
    int orig = blockIdx.x;
    int xcd = orig & 7;
    int loc = orig >> 3;
    int qq = nwg >> 3, rr = nwg & 7;
    int tile = (xcd < rr ? xcd * (qq + 1) : rr * (qq + 1) + (xcd - rr) * qq) + loc;
    int e0 = tile * 64;
    int l = t & 63, w = t >> 6, n0 = w * 32;
    // stage e1 = relu(P'[src] + Q[dst]) — 16 contiguous lanes cover one 256B row:
    // instruction i: lane (g=l>>4, c=l&15) reads edge (w*16 + i*4 + g) chunk c*16B.
    // Wave-level: 16 lanes x 16B contiguous -> 2x128B transactions per row (8x fewer).
    {
        int g = l >> 4, c = l & 15;
        #pragma unroll
        for (int i = 0; i < 4; ++i) {
            int le = w * 16 + i * 4 + g;
            int ge = min(e0 + le, E - 1);
            int sc = srcS[ge], dj = dstS[ge];
            half8 pv = *reinterpret_cast<const half8*>(P + (size_t)sc * 128 + c * 8);
            half8 qv = *reinterpret_cast<const half8*>(Q + (size_t)dj * 128 + c * 8);
            half8 sv = pv + qv;
            #pragma unroll
            for (int k = 0; k < 8; ++k)
                sv[k] = sv[k] > (f16)0 ? sv[k] : (f16)0;
            *reinterpret_cast<half8*>(&e1s[le * E1S + c * 8]) = sv;
        }
    }
    half8 bfrag[2][4];
    #pragma unroll
    for (int nt = 0; nt < 2; ++nt) {
        int col = n0 + nt * 16 + (l & 15);
        #pragma unroll
        for (int kt = 0; kt < 4; ++kt)
            bfrag[nt][kt] = *reinterpret_cast<const half8*>(Wt + col * 128 + kt * 32 + (l >> 4) * 8);
    }
    float bias0 = b1_2[n0 + (l & 15)];
    float bias1 = b1_2[n0 + 16 + (l & 15)];
    __syncthreads();
    f32x4 acc[4][2];
    #pragma unroll
    for (int mt = 0; mt < 4; ++mt) { acc[mt][0] = (f32x4){0,0,0,0}; acc[mt][1] = (f32x4){0,0,0,0}; }
    #pragma unroll
    for (int mt = 0; mt < 4; ++mt) {
        int arow = mt * 16 + (l & 15);
        #pragma unroll
        for (int kt = 0; kt < 4; ++kt) {
            half8 af = *reinterpret_cast<const half8*>(&e1s[arow * E1S + kt * 32 + (l >> 4) * 8]);
            acc[mt][0] = __builtin_amdgcn_mfma_f32_16x16x32_f16(af, bfrag[0][kt], acc[mt][0], 0, 0, 0);
            acc[mt][1] = __builtin_amdgcn_mfma_f32_16x16x32_f16(af, bfrag[1][kt], acc[mt][1], 0, 0, 0);
        }
    }
    #pragma unroll
    for (int mt = 0; mt < 4; ++mt)
        #pragma unroll
        for (int j = 0; j < 4; ++j) {
            acc[mt][0][j] = fmaxf(acc[mt][0][j] + bias0, 0.f);
            acc[mt][1][j] = fmaxf(acc[mt][1][j] + bias1, 0.f);
        }
    // in-register segmented reduce over MFMA rows (= edges), mt-tile skipped
    int myv = (e0 + l < E) ? srcS[e0 + l] : -1;
    int pv = __shfl_up(myv, 1, 64);
    bool head = (l == 0) || (myv != pv);
    unsigned long long validm = __ballot(myv >= 0);
    unsigned long long hm = __ballot(head) & validm;
    int nvalid = __popcll(validm);
    int grp = l >> 4;
    while (hm) {
        int lo = __builtin_ctzll(hm);
        hm &= hm - 1;
        int hi = hm ? __builtin_ctzll(hm) : nvalid;
        int s = __shfl(myv, lo, 64);
        float v0 = 0.f, v1 = 0.f;
        #pragma unroll
        for (int mt = 0; mt < 4; ++mt) {
            int tlo = mt * 16, thi = mt * 16 + 16;
            if (thi <= lo || tlo >= hi) continue;          // wave-uniform skip
            if (lo <= tlo && hi >= thi) {                  // full tile: plain adds
                #pragma unroll
                for (int j = 0; j < 4; ++j) {
                    v0 += acc[mt][0][j];
                    v1 += acc[mt][1][j];
                }
            } else {                                       // partial tile: masked adds
                #pragma unroll
                for (int j = 0; j < 4; ++j) {
                    int row = tlo + grp * 4 + j;
                    bool in = (row >= lo) && (row < hi);
                    v0 += in ? acc[mt][0][j] : 0.f;
                    v1 += in ? acc[mt][1][j] : 0.f;
                }
            }
        }
        v0 += __shfl_xor(v0, 16, 64); v0 += __shfl_xor(v0, 32, 64);
        v1 += __shfl_xor(v1, 16, 64); v1 += __shfl_xor(v1, 32, 64);
        if (l < 16) {
            int rs = rowptr[s], re = rowptr[s + 1];
            float* cp = C + (size_t)s * 128 + n0 + l;
            if (rs >= e0 && re <= e0 + 64) {
                cp[0] = v0; cp[16] = v1;
            } else {
                atomicAdd(cp, v0); atomicAdd(cp + 16, v1);
            }
        }
    }
}

// ---------------- K5: fused node curvature, 4-slot + prefetch, HT-interleaved gathers ----------------
__global__ void k_node_curv(const int* __restrict__ dstS, const int* __restrict__ rowptr,
                            const f16* __restrict__ HT, const f16* __restrict__ Rb,
                            const float* __restrict__ w2_2, const float* __restrict__ b2_2,
                            float* __restrict__ out, int N) {
    int node = blockIdx.x * 4 + (threadIdx.x >> 6);
    int lane = threadIdx.x & 63;
    if (node >= N) return;
    int sub = lane & 15;
    int slot = lane >> 4;
    const uint4* HTU = reinterpret_cast<const uint4*>(HT);
    uint4 hiu = HTU[(size_t)node * 32 + sub];
    uint4 rvu = reinterpret_cast<const uint4*>(Rb)[(size_t)node * 16 + sub];
    float hif[8], rvf[8], wvf[8];
    {
        const uint* hp = &hiu.x;
        const uint* rp = &rvu.x;
        float4 w0 = reinterpret_cast<const float4*>(w2_2)[sub * 2];
        float4 w1 = reinterpret_cast<const float4*>(w2_2)[sub * 2 + 1];
        #pragma unroll
        for (int k = 0; k < 4; ++k) {
            float2 h = up2(hp[k]); hif[k * 2] = h.x; hif[k * 2 + 1] = h.y;
            float2 r = up2(rp[k]); rvf[k * 2] = r.x; rvf[k * 2 + 1] = r.y;
        }
        wvf[0] = w0.x; wvf[1] = w0.y; wvf[2] = w0.z; wvf[3] = w0.w;
        wvf[4] = w1.x; wvf[5] = w1.y; wvf[6] = w1.z; wvf[7] = w1.w;
    }
    float bb = b2_2[0];
    int lo = rowptr[node], hiE = rowptr[node + 1];
    int deg = hiE - lo;
    float ax[8];
    #pragma unroll
    for (int j = 0; j < 8; ++j) ax[j] = 0.f;
    float sc = 0.f;
    int e = lo + slot;
    bool valid = e < hiE;
    int dcur = valid ? dstS[e] : 0;
    uint4 hju = HTU[(size_t)dcur * 32 + sub];
    uint4 tvu = HTU[(size_t)dcur * 32 + 16 + sub];
    for (int it = 0; it < deg; it += 4) {
        int e2 = lo + it + 4 + slot;
        bool valid2 = e2 < hiE;
        int d2 = valid2 ? dstS[e2] : 0;
        uint4 hjN = HTU[(size_t)d2 * 32 + sub];
        uint4 tvN = HTU[(size_t)d2 * 32 + 16 + sub];
        float hjf[8];
        float pcos = 0.f, pcur = 0.f;
        {
            const uint* hp = &hju.x;
            const uint* tp = &tvu.x;
            #pragma unroll
            for (int k = 0; k < 4; ++k) {
                float2 h = up2(hp[k]);
                float2 tv = up2(tp[k]);
                hjf[k * 2] = h.x; hjf[k * 2 + 1] = h.y;
                pcos += hif[k * 2] * h.x + hif[k * 2 + 1] * h.y;
                pcur += fmaxf(rvf[k * 2] + tv.x, 0.f) * wvf[k * 2]
                      + fmaxf(rvf[k * 2 + 1] + tv.y, 0.f) * wvf[k * 2 + 1];
            }
        }
        #pragma unroll
        for (int off = 1; off < 16; off <<= 1) {
            pcos += __shfl_xor(pcos, off, 64);
            pcur += __shfl_xor(pcur, off, 64);
        }
        float cur = valid ? (pcur + bb) : 0.f;
        #pragma unroll
        for (int j = 0; j < 8; ++j) ax[j] += cur * hjf[j];
        sc += cur * pcos;
        hju = hjN; tvu = tvN; valid = valid2;
    }
    #pragma unroll
    for (int j = 0; j < 8; ++j) {
        ax[j] += __shfl_xor(ax[j], 16, 64);
        ax[j] += __shfl_xor(ax[j], 32, 64);
    }
    sc += __shfl_xor(sc, 16, 64);
    sc += __shfl_xor(sc, 32, 64);
    float inv = 1.0f / fmaxf((float)deg, 1.0f);
    float ss = 0.f;
    #pragma unroll
    for (int j = 0; j < 8; ++j) {
        ax[j] = (ax[j] - sc * hif[j]) * inv;
        ss += ax[j] * ax[j];
    }
    #pragma unroll
    for (int off = 1; off < 16; off <<= 1) ss += __shfl_xor(ss, off, 64);
    float scale = 1.0f / (sqrtf(ss) + EPS);
    if (slot == 0) {
        float4 o0 = make_float4(ax[0] * scale, ax[1] * scale, ax[2] * scale, ax[3] * scale);
        float4 o1 = make_float4(ax[4] * scale, ax[5] * scale, ax[6] * scale, ax[7] * scale);
        float4* op = reinterpret_cast<float4*>(out + (size_t)node * 128 + sub * 8);
        op[0] = o0;
        op[1] = o1;
    }
}

extern "C" void kernel_launch(void* const* d_in, const int* in_sizes, int n_in,
                              void* d_out, int out_size, void* d_ws, size_t ws_size,
                              hipStream_t stream) {
    const float* H    = (const float*)d_in[1];
    const int*   ei   = (const int*)d_in[2];
    const float* w1_1 = (const float*)d_in[3];
    const float* b1_1 = (const float*)d_in[4];
    const float* w1_2 = (const float*)d_in[5];
    const float* b1_2 = (const float*)d_in[6];
    const float* w2_1 = (const float*)d_in[7];
    const float* b2_1 = (const float*)d_in[8];
    const float* w2_2 = (const float*)d_in[9];
    const float* b2_2 = (const float*)d_in[10];

    int N = in_sizes[1] / D;
    int E = in_sizes[2] / 2;
    const int* src = ei;
    const int* dst = ei + E;

    float* out = (float*)d_out;

    // Workspace layout
    f16* HT     = (f16*)d_ws;                     // N*256 fp16: [Hn | T]
    f16* Pb     = HT + (size_t)N * 256;           // N*128 fp16 (P', later R')
    f16* Qb     = Pb + (size_t)N * D;             // N*128 fp16 (Q)
    float* Cb   = (float*)(Qb + (size_t)N * D);   // N*128 fp32
    f16* Wt     = (f16*)(Cb + (size_t)N * D);     // 5 * 128*128 fp16
    int* deg    = (int*)(Wt + 5 * 16384);         // N
    int* rowptr = deg + N;                        // N+1
    int* fill   = rowptr + N + 1;                 // N
    int* srcS   = fill + N;                       // E
    int* dstS   = srcS + E;                       // E

    hipMemsetAsync(Cb, 0, (size_t)N * D * sizeof(float), stream);
    hipMemsetAsync(deg, 0, (3 * (size_t)N + 1) * sizeof(int), stream);

    int nbN = (N + 3) / 4;
    k_prologue<<<nbN + 1024 + 320, 256, 0, stream>>>(H, HT, src, deg,
                                                     w1_1, w1_2, w2_1, Wt, N, E, nbN);
    k_scan<<<1, 1024, 0, stream>>>(deg, rowptr, N);
    k_scatter<<<1024, 256, 0, stream>>>(src, dst, rowptr, fill, srcS, dstS, E);

    k_gemm_dual<true><<<(N + 63) / 64, 256, 0, stream>>>(HT, Wt + 0 * 16384, Wt + 1 * 16384,
                                                         b1_1, Pb, Qb, N, 256, 128);
    k_edge_mlp1<<<(E + 63) / 64, 256, 0, stream>>>(srcS, dstS, rowptr, Pb, Qb,
                                                   Wt + 2 * 16384, b1_2, Cb, E);
    k_gemm_dual<false><<<(N + 63) / 64, 256, 0, stream>>>(Cb, Wt + 3 * 16384, Wt + 4 * 16384,
                                                          b2_1, Pb, HT + 128, N, 128, 256);
    k_node_curv<<<(N + 3) / 4, 256, 0, stream>>>(dstS, rowptr, HT, Pb, w2_2, b2_2, out, N);
}